// Round 10
// baseline (165.852 us; speedup 1.0000x reference)
//
#include <hip/hip_runtime.h>

#define BB 4
#define NN 512
#define FF 64

typedef __attribute__((ext_vector_type(8))) short short8v;   // 8 bf16 = 4 VGPR
typedef __attribute__((ext_vector_type(4))) float f32x4;

__device__ __forceinline__ float silu_f(float v) {
  return v * __builtin_amdgcn_rcpf(1.0f + __expf(-v));
}
__device__ __forceinline__ unsigned short f2bf(float f) {
  unsigned int u = __float_as_uint(f);
  unsigned int r = (u + 0x7FFFu + ((u >> 16) & 1u)) >> 16;   // RNE (prep kernel only)
  return (unsigned short)r;
}
__device__ __forceinline__ float bf2f(unsigned short s) {
  return __uint_as_float(((unsigned int)s) << 16);
}
// packed f32x2 -> bf16x2 (RNE), low16 = a
__device__ __forceinline__ unsigned cvt_pk_bf16(float a, float b) {
  unsigned r;
  asm("v_cvt_pk_bf16_f32 %0, %1, %2" : "=v"(r) : "v"(a), "v"(b));
  return r;
}

// act LDS addressing: [j][k] bf16 rows of 128B, 16B slots XOR-swizzled by j. j in 0..127.
#define AIDX(j, k) ((((j) << 6)) | (((((k) >> 3) ^ ((j) & 7))) << 3) | ((k) & 7))

// ---------------- prep kernel (unchanged) ----------------
__global__ void sake_prep(const float* __restrict__ h, const float* __restrict__ We1,
                          const float* __restrict__ be1, const float* __restrict__ We2,
                          const float* __restrict__ Wc1, const float* __restrict__ Wc2,
                          float* __restrict__ G, float* __restrict__ Base,
                          unsigned short* __restrict__ w2h, unsigned short* __restrict__ w2l,
                          unsigned short* __restrict__ w3h, unsigned short* __restrict__ w3l,
                          unsigned short* __restrict__ w4h, unsigned short* __restrict__ w4l)
{
  const int wg = (int)blockIdx.x, tid = (int)threadIdx.x;
  if (wg < 64) {
    __shared__ float sH[32][64];
    const int r0 = wg * 32;
    for (int idx = tid; idx < 2048; idx += 256) sH[idx >> 6][idx & 63] = h[r0 * 64 + idx];
    __syncthreads();
    const int rl = tid >> 3;
    const int o0 = (tid & 7) * 8;
    float aG[8], aB[8];
    #pragma unroll
    for (int o = 0; o < 8; ++o) { aG[o] = 0.f; aB[o] = be1[o0 + o]; }
    for (int k = 0; k < 64; ++k) {
      const float hv = sH[rl][k];
      const float4 g0 = *(const float4*)&We1[k * 64 + o0];
      const float4 g1 = *(const float4*)&We1[k * 64 + o0 + 4];
      const float4 b0 = *(const float4*)&We1[(64 + k) * 64 + o0];
      const float4 b1 = *(const float4*)&We1[(64 + k) * 64 + o0 + 4];
      aG[0] = fmaf(hv, g0.x, aG[0]); aG[1] = fmaf(hv, g0.y, aG[1]);
      aG[2] = fmaf(hv, g0.z, aG[2]); aG[3] = fmaf(hv, g0.w, aG[3]);
      aG[4] = fmaf(hv, g1.x, aG[4]); aG[5] = fmaf(hv, g1.y, aG[5]);
      aG[6] = fmaf(hv, g1.z, aG[6]); aG[7] = fmaf(hv, g1.w, aG[7]);
      aB[0] = fmaf(hv, b0.x, aB[0]); aB[1] = fmaf(hv, b0.y, aB[1]);
      aB[2] = fmaf(hv, b0.z, aB[2]); aB[3] = fmaf(hv, b0.w, aB[3]);
      aB[4] = fmaf(hv, b1.x, aB[4]); aB[5] = fmaf(hv, b1.y, aB[5]);
      aB[6] = fmaf(hv, b1.z, aB[6]); aB[7] = fmaf(hv, b1.w, aB[7]);
    }
    const size_t base = (size_t)(r0 + rl) * 64 + o0;
    *(float4*)&G[base]        = make_float4(aG[0], aG[1], aG[2], aG[3]);
    *(float4*)&G[base + 4]    = make_float4(aG[4], aG[5], aG[6], aG[7]);
    *(float4*)&Base[base]     = make_float4(aB[0], aB[1], aB[2], aB[3]);
    *(float4*)&Base[base + 4] = make_float4(aB[4], aB[5], aB[6], aB[7]);
  } else {
    for (int idx = tid; idx < 10240; idx += 256) {
      float w; unsigned short *ph, *pl; int pos;
      if (idx < 4096)      { const int o = idx >> 6,          k = idx & 63;
                             w = We2[k * 64 + o]; ph = w2h; pl = w2l; pos = o * 64 + k; }
      else if (idx < 8192) { const int t = idx - 4096, o = t >> 6, k = t & 63;
                             w = Wc1[k * 64 + o]; ph = w3h; pl = w3l; pos = o * 64 + k; }
      else                 { const int t = idx - 8192, c = t >> 6, k = t & 63;
                             w = Wc2[k * 32 + c]; ph = w4h; pl = w4l; pos = c * 64 + k; }
      const unsigned short hi = f2bf(w);
      const unsigned short lo = f2bf(w - bf2f(hi));
      ph[pos] = hi; pl[pos] = lo;
    }
  }
}

__device__ __forceinline__ void pack_store4(unsigned short* sA, int a,
                                            float v0, float v1, float v2, float v3) {
  *(uint2*)&sA[a] = make_uint2(cvt_pk_bf16(v0, v1), cvt_pk_bf16(v2, v3));
}

// ---------------- main kernel ----------------
// TILE=128 (4 tiles), 2-buffer ping-pong, 4 barriers/tile.
// SESSION FINDING: launch_bounds 2nd arg == blocks/CU for 256-thr blocks and
// the CP pins residency there (R5/R8/R9 all 29%@(,3); R4 39%@(,4); R6 52%@(,6)).
// But as a MIN it lets the allocator over-shrink VGPRs (R4: 64 VGPR + 55MB
// spills; R9: 84 despite 168 cap -> no ILS/prefetch depth).
// Fix: amdgpu_waves_per_eu(4,4) EXACT -> 4 blocks/CU (LDS 36.4x4=145<=160 OK)
// AND a hard 128-VGPR budget the allocator won't undercut (natural ~96-110).
__global__ __launch_bounds__(256) __attribute__((amdgpu_waves_per_eu(4, 4)))
void sake_mfma(const float* __restrict__ h, const float* __restrict__ x,
               const float* __restrict__ mask,
               const float* __restrict__ We1, const float* __restrict__ be2,
               const float* __restrict__ bc1, const float* __restrict__ bc2,
               const float* __restrict__ Wp1, const float* __restrict__ bp1,
               const float* __restrict__ Wp2, const float* __restrict__ bp2,
               const float* __restrict__ Wn1, const float* __restrict__ bn1,
               const float* __restrict__ Wn2, const float* __restrict__ bn2,
               const float* __restrict__ G, const float* __restrict__ Base,
               const unsigned short* __restrict__ w2h, const unsigned short* __restrict__ w2l,
               const unsigned short* __restrict__ w3h, const unsigned short* __restrict__ w3l,
               const unsigned short* __restrict__ w4h, const unsigned short* __restrict__ w4l,
               float* __restrict__ out)
{
  __shared__ unsigned short sAct[2 * 8192];  // bufA | bufB, [j 0..127][k 0..63] swizzled
  __shared__ float sMaskL[128];
  __shared__ float sBase[64], sW1n[64], sHi[64];
  __shared__ float sB2[64], sB3[64], sB4[32];
  __shared__ float sHe[64], sCombP[4][48], sCN[32], sTmp[64], sHcomb[64];

  const int tid  = (int)threadIdx.x;
  const int blk  = (int)blockIdx.x;
  const int b    = blk >> 9;
  const int i    = blk & 511;
  const int lane = tid & 63;
  const int wid  = tid >> 6;
  const int l15  = lane & 15;
  const int lg   = lane >> 4;            // 0..3
  const int mb   = wid * 16;             // feat block (L2/C1)
  const int m2   = wid & 1;              // c-block (C2)
  const int jh   = (wid >> 1) * 16;      // C2 j sub-block

  const size_t mrow = ((size_t)(b * NN + i)) * NN;

  if (tid < 64) {
    sBase[tid] = Base[((size_t)(b * NN + i)) * 64 + tid];
    sW1n[tid]  = We1[128 * 64 + tid];
    sHi[tid]   = h[((size_t)(b * NN + i)) * 64 + tid];
    sB2[tid]   = be2[tid];
    sB3[tid]   = bc1[tid];
  }
  if (tid < 32) sB4[tid] = bc2[tid];
  const float xi0 = x[((size_t)(b * NN + i)) * 3 + 0];
  const float xi1 = x[((size_t)(b * NN + i)) * 3 + 1];
  const float xi2 = x[((size_t)(b * NN + i)) * 3 + 2];

  // weight A-frags in registers: w2/w3 full (16 feats per wave), w4 one c-block
  short8v w2hF[2], w2lF[2], w3hF[2], w3lF[2], w4hF[2], w4lF[2];
  #pragma unroll
  for (int ks = 0; ks < 2; ++ks) {
    const int ko = ks * 32 + lg * 8;
    w2hF[ks] = *(const short8v*)&w2h[(mb + l15) * 64 + ko];
    w2lF[ks] = *(const short8v*)&w2l[(mb + l15) * 64 + ko];
    w3hF[ks] = *(const short8v*)&w3h[(mb + l15) * 64 + ko];
    w3lF[ks] = *(const short8v*)&w3l[(mb + l15) * 64 + ko];
    w4hF[ks] = *(const short8v*)&w4h[(m2 * 16 + l15) * 64 + ko];
    w4lF[ks] = *(const short8v*)&w4l[(m2 * 16 + l15) * 64 + ko];
  }

  float heAcc[4] = {0.f, 0.f, 0.f, 0.f};
  float cAcc[4][3] = {};

  __syncthreads();   // prologue staging complete

  for (int jt = 0; jt < 4; ++jt) {
    const int jb = jt * 128;

    // ---- L1: act1 = silu(G + Base + n2*We1n) -> bufA ; stash mask ----
    #pragma unroll
    for (int jj = 0; jj < 2; ++jj) {
      const int jloc = jj * 64 + wid * 16 + l15;
      const int j = jb + jloc;
      const size_t xo = ((size_t)(b * NN + j)) * 3;
      const float dx = x[xo + 0] - xi0;
      const float dy = x[xo + 1] - xi1;
      const float dz = x[xo + 2] - xi2;
      const float n2 = dx * dx + dy * dy + dz * dz;
      if (lg == 0) sMaskL[jloc] = mask[mrow + j];
      #pragma unroll
      for (int kk = 0; kk < 4; ++kk) {
        const int kb = lg * 16 + kk * 4;
        const float4 g4 = *(const float4*)&G[((size_t)(b * NN + j)) * 64 + kb];
        const float4 bs = *(const float4*)&sBase[kb];
        const float4 wn = *(const float4*)&sW1n[kb];
        const float v0 = silu_f(g4.x + bs.x + n2 * wn.x);
        const float v1 = silu_f(g4.y + bs.y + n2 * wn.y);
        const float v2 = silu_f(g4.z + bs.z + n2 * wn.z);
        const float v3 = silu_f(g4.w + bs.w + n2 * wn.w);
        pack_store4(sAct, AIDX(jloc, kb), v0, v1, v2, v3);
      }
    }
    __syncthreads();   // B: bufA + sMaskL ready

    // ---- L2: bufA -> bufB ; h_e accum ----
    {
      const f32x4 bias = *(const f32x4*)&sB2[mb + lg * 4];
      #pragma unroll
      for (int nf = 0; nf < 8; ++nf) {
        const int jn = nf * 16 + l15;
        f32x4 acc = bias;
        #pragma unroll
        for (int ks = 0; ks < 2; ++ks) {
          const short8v bh = *(const short8v*)&sAct[AIDX(jn, ks * 32 + lg * 8)];
          acc = __builtin_amdgcn_mfma_f32_16x16x32_bf16(w2hF[ks], bh, acc, 0, 0, 0);
          acc = __builtin_amdgcn_mfma_f32_16x16x32_bf16(w2lF[ks], bh, acc, 0, 0, 0);
        }
        const float m = sMaskL[jn];
        float v[4];
        #pragma unroll
        for (int r = 0; r < 4; ++r) { v[r] = silu_f(acc[r]); heAcc[r] = fmaf(v[r], m, heAcc[r]); }
        pack_store4(sAct, 8192 + AIDX(jn, mb + lg * 4), v[0], v[1], v[2], v[3]);
      }
    }
    __syncthreads();   // C: bufB ready (all bufA reads done)

    // ---- C1: bufB -> bufA ----
    {
      const f32x4 bias = *(const f32x4*)&sB3[mb + lg * 4];
      #pragma unroll
      for (int nf = 0; nf < 8; ++nf) {
        const int jn = nf * 16 + l15;
        f32x4 acc = bias;
        #pragma unroll
        for (int ks = 0; ks < 2; ++ks) {
          const short8v bh = *(const short8v*)&sAct[8192 + AIDX(jn, ks * 32 + lg * 8)];
          acc = __builtin_amdgcn_mfma_f32_16x16x32_bf16(w3hF[ks], bh, acc, 0, 0, 0);
          acc = __builtin_amdgcn_mfma_f32_16x16x32_bf16(w3lF[ks], bh, acc, 0, 0, 0);
        }
        float v[4];
        #pragma unroll
        for (int r = 0; r < 4; ++r) v[r] = silu_f(acc[r]);
        pack_store4(sAct, AIDX(jn, mb + lg * 4), v[0], v[1], v[2], v[3]);
      }
    }
    __syncthreads();   // D: bufA(act3) ready

    // ---- C2: bufA ; vec*mask recomputed IN-PHASE (no cross-barrier regs) ----
    {
      const f32x4 bias = *(const f32x4*)&sB4[m2 * 16 + lg * 4];
      #pragma unroll
      for (int jj = 0; jj < 4; ++jj) {
        const int jloc = jj * 32 + jh + l15;   // 0..127, all 8 j-blocks over 4 waves
        const int j = jb + jloc;
        const size_t xo = ((size_t)(b * NN + j)) * 3;
        const float dx = x[xo + 0] - xi0;
        const float dy = x[xo + 1] - xi1;
        const float dz = x[xo + 2] - xi2;
        const float n2 = dx * dx + dy * dy + dz * dz;
        const float inv = __builtin_amdgcn_rcpf(n2 * n2 + 1e-10f);
        const float m = mask[mrow + j];
        const float vm0 = dx * inv * m, vm1 = dy * inv * m, vm2 = dz * inv * m;
        const short8v bh0 = *(const short8v*)&sAct[AIDX(jloc, lg * 8)];
        const short8v bh1 = *(const short8v*)&sAct[AIDX(jloc, 32 + lg * 8)];
        f32x4 acc = bias;
        acc = __builtin_amdgcn_mfma_f32_16x16x32_bf16(w4hF[0], bh0, acc, 0, 0, 0);
        acc = __builtin_amdgcn_mfma_f32_16x16x32_bf16(w4lF[0], bh0, acc, 0, 0, 0);
        acc = __builtin_amdgcn_mfma_f32_16x16x32_bf16(w4hF[1], bh1, acc, 0, 0, 0);
        acc = __builtin_amdgcn_mfma_f32_16x16x32_bf16(w4lF[1], bh1, acc, 0, 0, 0);
        #pragma unroll
        for (int r = 0; r < 4; ++r) {
          cAcc[r][0] = fmaf(acc[r], vm0, cAcc[r][0]);
          cAcc[r][1] = fmaf(acc[r], vm1, cAcc[r][1]);
          cAcc[r][2] = fmaf(acc[r], vm2, cAcc[r][2]);
        }
      }
    }
    __syncthreads();   // E: C2 reads of bufA done (next L1 overwrites bufA)
  }

  // -------- reductions --------
  #pragma unroll
  for (int r = 0; r < 4; ++r) {
    float s = heAcc[r];
    s += __shfl_xor(s, 1); s += __shfl_xor(s, 2); s += __shfl_xor(s, 4); s += __shfl_xor(s, 8);
    if (l15 == 0) sHe[mb + lg * 4 + r] = s;
  }
  #pragma unroll
  for (int r = 0; r < 4; ++r)
    #pragma unroll
    for (int d = 0; d < 3; ++d) {
      float s = cAcc[r][d];
      s += __shfl_xor(s, 1); s += __shfl_xor(s, 2); s += __shfl_xor(s, 4); s += __shfl_xor(s, 8);
      if (l15 == 0) sCombP[wid][(lg * 4 + r) * 3 + d] = s;
    }
  __syncthreads();
  if (tid < 32) {
    const int c = tid, cm2 = c >> 4, cl = c & 15;
    const float s0 = sCombP[cm2][cl * 3 + 0] + sCombP[cm2 + 2][cl * 3 + 0];
    const float s1 = sCombP[cm2][cl * 3 + 1] + sCombP[cm2 + 2][cl * 3 + 1];
    const float s2 = sCombP[cm2][cl * 3 + 2] + sCombP[cm2 + 2][cl * 3 + 2];
    sCN[c] = s0 * s0 + s1 * s1 + s2 * s2;
  }
  __syncthreads();

  // -------- epilogue MLPs (fp32, tiny) --------
  if (tid < 64) {
    float s = bp1[tid];
    #pragma unroll 8
    for (int c = 0; c < 32; ++c) s = fmaf(sCN[c], Wp1[c * 64 + tid], s);
    sTmp[tid] = silu_f(s);
  }
  __syncthreads();
  if (tid < 64) {
    float s = bp2[tid];
    #pragma unroll 16
    for (int k = 0; k < 64; ++k) s = fmaf(sTmp[k], Wp2[k * 64 + tid], s);
    sHcomb[tid] = s;
  }
  __syncthreads();
  if (tid < 64) {
    float s = bn1[tid];
    #pragma unroll 16
    for (int m = 0; m < 64; ++m) s = fmaf(sHi[m],    Wn1[m * 64 + tid],         s);
    #pragma unroll 16
    for (int m = 0; m < 64; ++m) s = fmaf(sHe[m],    Wn1[(64 + m) * 64 + tid],  s);
    #pragma unroll 16
    for (int m = 0; m < 64; ++m) s = fmaf(sHcomb[m], Wn1[(128 + m) * 64 + tid], s);
    sTmp[tid] = silu_f(s);
  }
  __syncthreads();
  if (tid < 64) {
    float s = bn2[tid];
    #pragma unroll 16
    for (int k = 0; k < 64; ++k) s = fmaf(sTmp[k], Wn2[k * 64 + tid], s);
    out[((size_t)(b * NN + i)) * 64 + tid] = sHi[tid] + s;
  } else if (tid < 67) {
    const int d = tid - 64;
    out[(size_t)BB * NN * FF + ((size_t)(b * NN + i)) * 3 + d] = x[((size_t)(b * NN + i)) * 3 + d];
  }
}

extern "C" void kernel_launch(void* const* d_in, const int* in_sizes, int n_in,
                              void* d_out, int out_size, void* d_ws, size_t ws_size,
                              hipStream_t stream) {
  const float* h    = (const float*)d_in[0];
  const float* x    = (const float*)d_in[1];
  const float* mask = (const float*)d_in[2];
  const float* We1  = (const float*)d_in[3];
  const float* be1  = (const float*)d_in[4];
  const float* We2  = (const float*)d_in[5];
  const float* be2  = (const float*)d_in[6];
  const float* Wc1  = (const float*)d_in[7];
  const float* bc1  = (const float*)d_in[8];
  const float* Wc2  = (const float*)d_in[9];
  const float* bc2  = (const float*)d_in[10];
  const float* Wp1  = (const float*)d_in[11];
  const float* bp1  = (const float*)d_in[12];
  const float* Wp2  = (const float*)d_in[13];
  const float* bp2  = (const float*)d_in[14];
  const float* Wn1  = (const float*)d_in[15];
  const float* bn1  = (const float*)d_in[16];
  const float* Wn2  = (const float*)d_in[17];
  const float* bn2  = (const float*)d_in[18];
  float* out = (float*)d_out;

  float* G    = (float*)d_ws;                       // 2048*64 f32
  float* Base = G + 2048 * 64;                      // 2048*64 f32
  unsigned short* w2h = (unsigned short*)(Base + 2048 * 64);
  unsigned short* w2l = w2h + 4096;
  unsigned short* w3h = w2l + 4096;
  unsigned short* w3l = w3h + 4096;
  unsigned short* w4h = w3l + 4096;
  unsigned short* w4l = w4h + 2048;

  hipLaunchKernelGGL(sake_prep, dim3(65), dim3(256), 0, stream,
                     h, We1, be1, We2, Wc1, Wc2, G, Base,
                     w2h, w2l, w3h, w3l, w4h, w4l);
  hipLaunchKernelGGL(sake_mfma, dim3(BB * NN), dim3(256), 0, stream,
                     h, x, mask, We1, be2, bc1, bc2,
                     Wp1, bp1, Wp2, bp2, Wn1, bn1, Wn2, bn2,
                     G, Base, w2h, w2l, w3h, w3l, w4h, w4l, out);
}

// Round 11
// 127.215 us; speedup vs baseline: 1.3037x; 1.3037x over previous
//
#include <hip/hip_runtime.h>

#define BB 4
#define NN 512
#define FF 64

typedef __attribute__((ext_vector_type(8))) short short8v;   // 8 bf16 = 4 VGPR
typedef __attribute__((ext_vector_type(4))) float f32x4;

__device__ __forceinline__ float silu_f(float v) {
  return v * __builtin_amdgcn_rcpf(1.0f + __expf(-v));
}
__device__ __forceinline__ unsigned short f2bf(float f) {
  unsigned int u = __float_as_uint(f);
  unsigned int r = (u + 0x7FFFu + ((u >> 16) & 1u)) >> 16;   // RNE (prep kernel only)
  return (unsigned short)r;
}
__device__ __forceinline__ float bf2f(unsigned short s) {
  return __uint_as_float(((unsigned int)s) << 16);
}
// packed f32x2 -> bf16x2 (RNE), low16 = a
__device__ __forceinline__ unsigned cvt_pk_bf16(float a, float b) {
  unsigned r;
  asm("v_cvt_pk_bf16_f32 %0, %1, %2" : "=v"(r) : "v"(a), "v"(b));
  return r;
}

// act LDS addressing: [j][k] bf16 rows of 128B, 16B slots XOR-swizzled by j. j in 0..127.
#define AIDX(j, k) ((((j) << 6)) | (((((k) >> 3) ^ ((j) & 7))) << 3) | ((k) & 7))

// ---------------- prep kernel (unchanged) ----------------
__global__ void sake_prep(const float* __restrict__ h, const float* __restrict__ We1,
                          const float* __restrict__ be1, const float* __restrict__ We2,
                          const float* __restrict__ Wc1, const float* __restrict__ Wc2,
                          float* __restrict__ G, float* __restrict__ Base,
                          unsigned short* __restrict__ w2h, unsigned short* __restrict__ w2l,
                          unsigned short* __restrict__ w3h, unsigned short* __restrict__ w3l,
                          unsigned short* __restrict__ w4h, unsigned short* __restrict__ w4l)
{
  const int wg = (int)blockIdx.x, tid = (int)threadIdx.x;
  if (wg < 64) {
    __shared__ float sH[32][64];
    const int r0 = wg * 32;
    for (int idx = tid; idx < 2048; idx += 256) sH[idx >> 6][idx & 63] = h[r0 * 64 + idx];
    __syncthreads();
    const int rl = tid >> 3;
    const int o0 = (tid & 7) * 8;
    float aG[8], aB[8];
    #pragma unroll
    for (int o = 0; o < 8; ++o) { aG[o] = 0.f; aB[o] = be1[o0 + o]; }
    for (int k = 0; k < 64; ++k) {
      const float hv = sH[rl][k];
      const float4 g0 = *(const float4*)&We1[k * 64 + o0];
      const float4 g1 = *(const float4*)&We1[k * 64 + o0 + 4];
      const float4 b0 = *(const float4*)&We1[(64 + k) * 64 + o0];
      const float4 b1 = *(const float4*)&We1[(64 + k) * 64 + o0 + 4];
      aG[0] = fmaf(hv, g0.x, aG[0]); aG[1] = fmaf(hv, g0.y, aG[1]);
      aG[2] = fmaf(hv, g0.z, aG[2]); aG[3] = fmaf(hv, g0.w, aG[3]);
      aG[4] = fmaf(hv, g1.x, aG[4]); aG[5] = fmaf(hv, g1.y, aG[5]);
      aG[6] = fmaf(hv, g1.z, aG[6]); aG[7] = fmaf(hv, g1.w, aG[7]);
      aB[0] = fmaf(hv, b0.x, aB[0]); aB[1] = fmaf(hv, b0.y, aB[1]);
      aB[2] = fmaf(hv, b0.z, aB[2]); aB[3] = fmaf(hv, b0.w, aB[3]);
      aB[4] = fmaf(hv, b1.x, aB[4]); aB[5] = fmaf(hv, b1.y, aB[5]);
      aB[6] = fmaf(hv, b1.z, aB[6]); aB[7] = fmaf(hv, b1.w, aB[7]);
    }
    const size_t base = (size_t)(r0 + rl) * 64 + o0;
    *(float4*)&G[base]        = make_float4(aG[0], aG[1], aG[2], aG[3]);
    *(float4*)&G[base + 4]    = make_float4(aG[4], aG[5], aG[6], aG[7]);
    *(float4*)&Base[base]     = make_float4(aB[0], aB[1], aB[2], aB[3]);
    *(float4*)&Base[base + 4] = make_float4(aB[4], aB[5], aB[6], aB[7]);
  } else {
    for (int idx = tid; idx < 10240; idx += 256) {
      float w; unsigned short *ph, *pl; int pos;
      if (idx < 4096)      { const int o = idx >> 6,          k = idx & 63;
                             w = We2[k * 64 + o]; ph = w2h; pl = w2l; pos = o * 64 + k; }
      else if (idx < 8192) { const int t = idx - 4096, o = t >> 6, k = t & 63;
                             w = Wc1[k * 64 + o]; ph = w3h; pl = w3l; pos = o * 64 + k; }
      else                 { const int t = idx - 8192, c = t >> 6, k = t & 63;
                             w = Wc2[k * 32 + c]; ph = w4h; pl = w4l; pos = c * 64 + k; }
      const unsigned short hi = f2bf(w);
      const unsigned short lo = f2bf(w - bf2f(hi));
      ph[pos] = hi; pl[pos] = lo;
    }
  }
}

__device__ __forceinline__ void pack_store4(unsigned short* sA, int a,
                                            float v0, float v1, float v2, float v3) {
  *(uint2*)&sA[a] = make_uint2(cvt_pk_bf16(v0, v1), cvt_pk_bf16(v2, v3));
}

// ---------------- main kernel ----------------
// TILE=128 (4 tiles), 3 LDS act buffers A/B/C. Loop-top barrier REMOVED
// (safe: bufA/sMaskL writers in L1(t+1) are >=2 barriers past their last
// readers L2(t); C2(t)'s bufC reads are 2 barriers ahead of C1(t+1) writes)
// -> 3 barriers/tile, 12 total, and C2(t) overlaps L1(t+1) across waves.
// L1 is kk-outer/jj-inner so sBase/sW1n are loaded once per kk (explicit CSE);
// n2v[2] lives only within the L1 phase (no cross-barrier regs - R7 lesson).
// (256,3): session finding - any >=4 blocks/CU request crushes VGPR to 64 and
// spills (R4/R6/R10); 84-VGPR/3-block is the stable operating point.
__global__ __launch_bounds__(256, 3)
void sake_mfma(const float* __restrict__ h, const float* __restrict__ x,
               const float* __restrict__ mask,
               const float* __restrict__ We1, const float* __restrict__ be2,
               const float* __restrict__ bc1, const float* __restrict__ bc2,
               const float* __restrict__ Wp1, const float* __restrict__ bp1,
               const float* __restrict__ Wp2, const float* __restrict__ bp2,
               const float* __restrict__ Wn1, const float* __restrict__ bn1,
               const float* __restrict__ Wn2, const float* __restrict__ bn2,
               const float* __restrict__ G, const float* __restrict__ Base,
               const unsigned short* __restrict__ w2h, const unsigned short* __restrict__ w2l,
               const unsigned short* __restrict__ w3h, const unsigned short* __restrict__ w3l,
               const unsigned short* __restrict__ w4h, const unsigned short* __restrict__ w4l,
               float* __restrict__ out)
{
  __shared__ unsigned short sAct[3 * 8192];  // bufA | bufB | bufC, [j 0..127][k 0..63] swizzled
  __shared__ float sMaskL[128];
  __shared__ float sBase[64], sW1n[64], sHi[64];
  __shared__ float sB2[64], sB3[64], sB4[32];
  __shared__ float sHe[64], sCombP[4][48], sCN[32], sTmp[64], sHcomb[64];

  const int tid  = (int)threadIdx.x;
  const int blk  = (int)blockIdx.x;
  const int b    = blk >> 9;
  const int i    = blk & 511;
  const int lane = tid & 63;
  const int wid  = tid >> 6;
  const int l15  = lane & 15;
  const int lg   = lane >> 4;            // 0..3
  const int mb   = wid * 16;             // feat block (L2/C1)
  const int m2   = wid & 1;              // c-block (C2)
  const int jh   = (wid >> 1) * 16;      // C2 j sub-block

  const size_t mrow = ((size_t)(b * NN + i)) * NN;

  if (tid < 64) {
    sBase[tid] = Base[((size_t)(b * NN + i)) * 64 + tid];
    sW1n[tid]  = We1[128 * 64 + tid];
    sHi[tid]   = h[((size_t)(b * NN + i)) * 64 + tid];
    sB2[tid]   = be2[tid];
    sB3[tid]   = bc1[tid];
  }
  if (tid < 32) sB4[tid] = bc2[tid];
  const float xi0 = x[((size_t)(b * NN + i)) * 3 + 0];
  const float xi1 = x[((size_t)(b * NN + i)) * 3 + 1];
  const float xi2 = x[((size_t)(b * NN + i)) * 3 + 2];

  // weight A-frags in registers: w2/w3 full (16 feats per wave), w4 one c-block
  short8v w2hF[2], w2lF[2], w3hF[2], w3lF[2], w4hF[2], w4lF[2];
  #pragma unroll
  for (int ks = 0; ks < 2; ++ks) {
    const int ko = ks * 32 + lg * 8;
    w2hF[ks] = *(const short8v*)&w2h[(mb + l15) * 64 + ko];
    w2lF[ks] = *(const short8v*)&w2l[(mb + l15) * 64 + ko];
    w3hF[ks] = *(const short8v*)&w3h[(mb + l15) * 64 + ko];
    w3lF[ks] = *(const short8v*)&w3l[(mb + l15) * 64 + ko];
    w4hF[ks] = *(const short8v*)&w4h[(m2 * 16 + l15) * 64 + ko];
    w4lF[ks] = *(const short8v*)&w4l[(m2 * 16 + l15) * 64 + ko];
  }

  float heAcc[4] = {0.f, 0.f, 0.f, 0.f};
  float cAcc[4][3] = {};

  __syncthreads();   // prologue staging complete

  for (int jt = 0; jt < 4; ++jt) {
    const int jb = jt * 128;

    // ---- L1: act1 = silu(G + Base + n2*We1n) -> bufA ; stash mask ----
    // (no loop-top barrier: see header comment for the hazard proof)
    {
      float n2v[2];
      #pragma unroll
      for (int jj = 0; jj < 2; ++jj) {
        const int jloc = jj * 64 + wid * 16 + l15;
        const int j = jb + jloc;
        const size_t xo = ((size_t)(b * NN + j)) * 3;
        const float dx = x[xo + 0] - xi0;
        const float dy = x[xo + 1] - xi1;
        const float dz = x[xo + 2] - xi2;
        n2v[jj] = dx * dx + dy * dy + dz * dz;
        if (lg == 0) sMaskL[jloc] = mask[mrow + j];
      }
      #pragma unroll
      for (int kk = 0; kk < 4; ++kk) {
        const int kb = lg * 16 + kk * 4;
        const float4 bs = *(const float4*)&sBase[kb];
        const float4 wn = *(const float4*)&sW1n[kb];
        #pragma unroll
        for (int jj = 0; jj < 2; ++jj) {
          const int jloc = jj * 64 + wid * 16 + l15;
          const float4 g4 = *(const float4*)&G[((size_t)(b * NN + jb + jloc)) * 64 + kb];
          const float n2 = n2v[jj];
          const float v0 = silu_f(g4.x + bs.x + n2 * wn.x);
          const float v1 = silu_f(g4.y + bs.y + n2 * wn.y);
          const float v2 = silu_f(g4.z + bs.z + n2 * wn.z);
          const float v3 = silu_f(g4.w + bs.w + n2 * wn.w);
          pack_store4(sAct, AIDX(jloc, kb), v0, v1, v2, v3);
        }
      }
    }
    __syncthreads();   // B: bufA + sMaskL ready

    // ---- L2: bufA -> bufB ; h_e accum ----
    {
      const f32x4 bias = *(const f32x4*)&sB2[mb + lg * 4];
      #pragma unroll
      for (int nf = 0; nf < 8; ++nf) {
        const int jn = nf * 16 + l15;
        f32x4 acc = bias;
        #pragma unroll
        for (int ks = 0; ks < 2; ++ks) {
          const short8v bh = *(const short8v*)&sAct[AIDX(jn, ks * 32 + lg * 8)];
          acc = __builtin_amdgcn_mfma_f32_16x16x32_bf16(w2hF[ks], bh, acc, 0, 0, 0);
          acc = __builtin_amdgcn_mfma_f32_16x16x32_bf16(w2lF[ks], bh, acc, 0, 0, 0);
        }
        const float m = sMaskL[jn];
        float v[4];
        #pragma unroll
        for (int r = 0; r < 4; ++r) { v[r] = silu_f(acc[r]); heAcc[r] = fmaf(v[r], m, heAcc[r]); }
        pack_store4(sAct, 8192 + AIDX(jn, mb + lg * 4), v[0], v[1], v[2], v[3]);
      }
    }
    __syncthreads();   // C: bufB ready (all bufA reads done)

    // ---- C1: bufB -> bufC ----
    {
      const f32x4 bias = *(const f32x4*)&sB3[mb + lg * 4];
      #pragma unroll
      for (int nf = 0; nf < 8; ++nf) {
        const int jn = nf * 16 + l15;
        f32x4 acc = bias;
        #pragma unroll
        for (int ks = 0; ks < 2; ++ks) {
          const short8v bh = *(const short8v*)&sAct[8192 + AIDX(jn, ks * 32 + lg * 8)];
          acc = __builtin_amdgcn_mfma_f32_16x16x32_bf16(w3hF[ks], bh, acc, 0, 0, 0);
          acc = __builtin_amdgcn_mfma_f32_16x16x32_bf16(w3lF[ks], bh, acc, 0, 0, 0);
        }
        float v[4];
        #pragma unroll
        for (int r = 0; r < 4; ++r) v[r] = silu_f(acc[r]);
        pack_store4(sAct, 16384 + AIDX(jn, mb + lg * 4), v[0], v[1], v[2], v[3]);
      }
    }
    __syncthreads();   // D: bufC(act3) ready

    // ---- C2: bufC ; vec*mask recomputed IN-PHASE (no cross-barrier regs) ----
    {
      const f32x4 bias = *(const f32x4*)&sB4[m2 * 16 + lg * 4];
      #pragma unroll
      for (int jj = 0; jj < 4; ++jj) {
        const int jloc = jj * 32 + jh + l15;   // 0..127, all 8 j-blocks over 4 waves
        const int j = jb + jloc;
        const size_t xo = ((size_t)(b * NN + j)) * 3;
        const float dx = x[xo + 0] - xi0;
        const float dy = x[xo + 1] - xi1;
        const float dz = x[xo + 2] - xi2;
        const float n2 = dx * dx + dy * dy + dz * dz;
        const float inv = __builtin_amdgcn_rcpf(n2 * n2 + 1e-10f);
        const float m = mask[mrow + j];
        const float vm0 = dx * inv * m, vm1 = dy * inv * m, vm2 = dz * inv * m;
        const short8v bh0 = *(const short8v*)&sAct[16384 + AIDX(jloc, lg * 8)];
        const short8v bh1 = *(const short8v*)&sAct[16384 + AIDX(jloc, 32 + lg * 8)];
        f32x4 acc = bias;
        acc = __builtin_amdgcn_mfma_f32_16x16x32_bf16(w4hF[0], bh0, acc, 0, 0, 0);
        acc = __builtin_amdgcn_mfma_f32_16x16x32_bf16(w4lF[0], bh0, acc, 0, 0, 0);
        acc = __builtin_amdgcn_mfma_f32_16x16x32_bf16(w4hF[1], bh1, acc, 0, 0, 0);
        acc = __builtin_amdgcn_mfma_f32_16x16x32_bf16(w4lF[1], bh1, acc, 0, 0, 0);
        #pragma unroll
        for (int r = 0; r < 4; ++r) {
          cAcc[r][0] = fmaf(acc[r], vm0, cAcc[r][0]);
          cAcc[r][1] = fmaf(acc[r], vm1, cAcc[r][1]);
          cAcc[r][2] = fmaf(acc[r], vm2, cAcc[r][2]);
        }
      }
    }
    // no barrier: L1(t+1) touches only bufA/sMaskL, disjoint from C2(t)'s bufC
  }

  // -------- reductions --------
  __syncthreads();   // all waves' C2 done before reusing scratch/reduction LDS
  #pragma unroll
  for (int r = 0; r < 4; ++r) {
    float s = heAcc[r];
    s += __shfl_xor(s, 1); s += __shfl_xor(s, 2); s += __shfl_xor(s, 4); s += __shfl_xor(s, 8);
    if (l15 == 0) sHe[mb + lg * 4 + r] = s;
  }
  #pragma unroll
  for (int r = 0; r < 4; ++r)
    #pragma unroll
    for (int d = 0; d < 3; ++d) {
      float s = cAcc[r][d];
      s += __shfl_xor(s, 1); s += __shfl_xor(s, 2); s += __shfl_xor(s, 4); s += __shfl_xor(s, 8);
      if (l15 == 0) sCombP[wid][(lg * 4 + r) * 3 + d] = s;
    }
  __syncthreads();
  if (tid < 32) {
    const int c = tid, cm2 = c >> 4, cl = c & 15;
    const float s0 = sCombP[cm2][cl * 3 + 0] + sCombP[cm2 + 2][cl * 3 + 0];
    const float s1 = sCombP[cm2][cl * 3 + 1] + sCombP[cm2 + 2][cl * 3 + 1];
    const float s2 = sCombP[cm2][cl * 3 + 2] + sCombP[cm2 + 2][cl * 3 + 2];
    sCN[c] = s0 * s0 + s1 * s1 + s2 * s2;
  }
  __syncthreads();

  // -------- epilogue MLPs (fp32, tiny) --------
  if (tid < 64) {
    float s = bp1[tid];
    #pragma unroll 8
    for (int c = 0; c < 32; ++c) s = fmaf(sCN[c], Wp1[c * 64 + tid], s);
    sTmp[tid] = silu_f(s);
  }
  __syncthreads();
  if (tid < 64) {
    float s = bp2[tid];
    #pragma unroll 16
    for (int k = 0; k < 64; ++k) s = fmaf(sTmp[k], Wp2[k * 64 + tid], s);
    sHcomb[tid] = s;
  }
  __syncthreads();
  if (tid < 64) {
    float s = bn1[tid];
    #pragma unroll 16
    for (int m = 0; m < 64; ++m) s = fmaf(sHi[m],    Wn1[m * 64 + tid],         s);
    #pragma unroll 16
    for (int m = 0; m < 64; ++m) s = fmaf(sHe[m],    Wn1[(64 + m) * 64 + tid],  s);
    #pragma unroll 16
    for (int m = 0; m < 64; ++m) s = fmaf(sHcomb[m], Wn1[(128 + m) * 64 + tid], s);
    sTmp[tid] = silu_f(s);
  }
  __syncthreads();
  if (tid < 64) {
    float s = bn2[tid];
    #pragma unroll 16
    for (int k = 0; k < 64; ++k) s = fmaf(sTmp[k], Wn2[k * 64 + tid], s);
    out[((size_t)(b * NN + i)) * 64 + tid] = sHi[tid] + s;
  } else if (tid < 67) {
    const int d = tid - 64;
    out[(size_t)BB * NN * FF + ((size_t)(b * NN + i)) * 3 + d] = x[((size_t)(b * NN + i)) * 3 + d];
  }
}

extern "C" void kernel_launch(void* const* d_in, const int* in_sizes, int n_in,
                              void* d_out, int out_size, void* d_ws, size_t ws_size,
                              hipStream_t stream) {
  const float* h    = (const float*)d_in[0];
  const float* x    = (const float*)d_in[1];
  const float* mask = (const float*)d_in[2];
  const float* We1  = (const float*)d_in[3];
  const float* be1  = (const float*)d_in[4];
  const float* We2  = (const float*)d_in[5];
  const float* be2  = (const float*)d_in[6];
  const float* Wc1  = (const float*)d_in[7];
  const float* bc1  = (const float*)d_in[8];
  const float* Wc2  = (const float*)d_in[9];
  const float* bc2  = (const float*)d_in[10];
  const float* Wp1  = (const float*)d_in[11];
  const float* bp1  = (const float*)d_in[12];
  const float* Wp2  = (const float*)d_in[13];
  const float* bp2  = (const float*)d_in[14];
  const float* Wn1  = (const float*)d_in[15];
  const float* bn1  = (const float*)d_in[16];
  const float* Wn2  = (const float*)d_in[17];
  const float* bn2  = (const float*)d_in[18];
  float* out = (float*)d_out;

  float* G    = (float*)d_ws;                       // 2048*64 f32
  float* Base = G + 2048 * 64;                      // 2048*64 f32
  unsigned short* w2h = (unsigned short*)(Base + 2048 * 64);
  unsigned short* w2l = w2h + 4096;
  unsigned short* w3h = w2l + 4096;
  unsigned short* w3l = w3h + 4096;
  unsigned short* w4h = w3l + 4096;
  unsigned short* w4l = w4h + 2048;

  hipLaunchKernelGGL(sake_prep, dim3(65), dim3(256), 0, stream,
                     h, We1, be1, We2, Wc1, Wc2, G, Base,
                     w2h, w2l, w3h, w3l, w4h, w4l);
  hipLaunchKernelGGL(sake_mfma, dim3(BB * NN), dim3(256), 0, stream,
                     h, x, mask, We1, be2, bc1, bc2,
                     Wp1, bp1, Wp2, bp2, Wn1, bn1, Wn2, bn2,
                     G, Base, w2h, w2l, w3h, w3l, w4h, w4l, out);
}

// Round 12
// 125.039 us; speedup vs baseline: 1.3264x; 1.0174x over previous
//
#include <hip/hip_runtime.h>

#define BB 4
#define NN 512
#define FF 64

typedef __attribute__((ext_vector_type(8))) short short8v;   // 8 bf16 = 4 VGPR
typedef __attribute__((ext_vector_type(4))) float f32x4;

__device__ __forceinline__ float silu_f(float v) {
  return v * __builtin_amdgcn_rcpf(1.0f + __expf(-v));
}
__device__ __forceinline__ unsigned short f2bf(float f) {
  unsigned int u = __float_as_uint(f);
  unsigned int r = (u + 0x7FFFu + ((u >> 16) & 1u)) >> 16;   // RNE (prep kernel only)
  return (unsigned short)r;
}
__device__ __forceinline__ float bf2f(unsigned short s) {
  return __uint_as_float(((unsigned int)s) << 16);
}
// packed f32x2 -> bf16x2 (RNE), low16 = a
__device__ __forceinline__ unsigned cvt_pk_bf16(float a, float b) {
  unsigned r;
  asm("v_cvt_pk_bf16_f32 %0, %1, %2" : "=v"(r) : "v"(a), "v"(b));
  return r;
}

// act LDS addressing: [j][k] bf16 rows of 128B, 16B slots XOR-swizzled by j. j in 0..127.
#define AIDX(j, k) ((((j) << 6)) | (((((k) >> 3) ^ ((j) & 7))) << 3) | ((k) & 7))

// ---------------- prep kernel (unchanged) ----------------
__global__ void sake_prep(const float* __restrict__ h, const float* __restrict__ We1,
                          const float* __restrict__ be1, const float* __restrict__ We2,
                          const float* __restrict__ Wc1, const float* __restrict__ Wc2,
                          float* __restrict__ G, float* __restrict__ Base,
                          unsigned short* __restrict__ w2h, unsigned short* __restrict__ w2l,
                          unsigned short* __restrict__ w3h, unsigned short* __restrict__ w3l,
                          unsigned short* __restrict__ w4h, unsigned short* __restrict__ w4l)
{
  const int wg = (int)blockIdx.x, tid = (int)threadIdx.x;
  if (wg < 64) {
    __shared__ float sH[32][64];
    const int r0 = wg * 32;
    for (int idx = tid; idx < 2048; idx += 256) sH[idx >> 6][idx & 63] = h[r0 * 64 + idx];
    __syncthreads();
    const int rl = tid >> 3;
    const int o0 = (tid & 7) * 8;
    float aG[8], aB[8];
    #pragma unroll
    for (int o = 0; o < 8; ++o) { aG[o] = 0.f; aB[o] = be1[o0 + o]; }
    for (int k = 0; k < 64; ++k) {
      const float hv = sH[rl][k];
      const float4 g0 = *(const float4*)&We1[k * 64 + o0];
      const float4 g1 = *(const float4*)&We1[k * 64 + o0 + 4];
      const float4 b0 = *(const float4*)&We1[(64 + k) * 64 + o0];
      const float4 b1 = *(const float4*)&We1[(64 + k) * 64 + o0 + 4];
      aG[0] = fmaf(hv, g0.x, aG[0]); aG[1] = fmaf(hv, g0.y, aG[1]);
      aG[2] = fmaf(hv, g0.z, aG[2]); aG[3] = fmaf(hv, g0.w, aG[3]);
      aG[4] = fmaf(hv, g1.x, aG[4]); aG[5] = fmaf(hv, g1.y, aG[5]);
      aG[6] = fmaf(hv, g1.z, aG[6]); aG[7] = fmaf(hv, g1.w, aG[7]);
      aB[0] = fmaf(hv, b0.x, aB[0]); aB[1] = fmaf(hv, b0.y, aB[1]);
      aB[2] = fmaf(hv, b0.z, aB[2]); aB[3] = fmaf(hv, b0.w, aB[3]);
      aB[4] = fmaf(hv, b1.x, aB[4]); aB[5] = fmaf(hv, b1.y, aB[5]);
      aB[6] = fmaf(hv, b1.z, aB[6]); aB[7] = fmaf(hv, b1.w, aB[7]);
    }
    const size_t base = (size_t)(r0 + rl) * 64 + o0;
    *(float4*)&G[base]        = make_float4(aG[0], aG[1], aG[2], aG[3]);
    *(float4*)&G[base + 4]    = make_float4(aG[4], aG[5], aG[6], aG[7]);
    *(float4*)&Base[base]     = make_float4(aB[0], aB[1], aB[2], aB[3]);
    *(float4*)&Base[base + 4] = make_float4(aB[4], aB[5], aB[6], aB[7]);
  } else {
    for (int idx = tid; idx < 10240; idx += 256) {
      float w; unsigned short *ph, *pl; int pos;
      if (idx < 4096)      { const int o = idx >> 6,          k = idx & 63;
                             w = We2[k * 64 + o]; ph = w2h; pl = w2l; pos = o * 64 + k; }
      else if (idx < 8192) { const int t = idx - 4096, o = t >> 6, k = t & 63;
                             w = Wc1[k * 64 + o]; ph = w3h; pl = w3l; pos = o * 64 + k; }
      else                 { const int t = idx - 8192, c = t >> 6, k = t & 63;
                             w = Wc2[k * 32 + c]; ph = w4h; pl = w4l; pos = c * 64 + k; }
      const unsigned short hi = f2bf(w);
      const unsigned short lo = f2bf(w - bf2f(hi));
      ph[pos] = hi; pl[pos] = lo;
    }
  }
}

__device__ __forceinline__ void pack_store4(unsigned short* sA, int a,
                                            float v0, float v1, float v2, float v3) {
  *(uint2*)&sA[a] = make_uint2(cvt_pk_bf16(v0, v1), cvt_pk_bf16(v2, v3));
}

// ---------------- main kernel ----------------
// R8 base (best measured: 124.5us). TILE=128 (4 tiles), 2-buffer ping-pong,
// 4 barriers/tile, LDS 36.4KB.
// SESSION FINDING (R4/R6/R10/R12): allocator targets ~2x the declared
// occupancy: alloc ~= 512/(2*w) VGPR for request w. (256,3)->84, (256,4)->64
// (spill), (256,6)->40 (spill). At 84 VGPR the MFMA phases can't prefetch
// their 8 B-frags (64 VGPR) -> each nf iteration serializes on its ds_read.
// amdgpu_num_vgpr(128) overrides the ceiling: residency stays 3 blocks but
// the scheduler gets room to software-pipeline. 128 VGPR still = 4 waves/SIMD.
__global__ __launch_bounds__(256, 3) __attribute__((amdgpu_num_vgpr(128)))
void sake_mfma(const float* __restrict__ h, const float* __restrict__ x,
               const float* __restrict__ mask,
               const float* __restrict__ We1, const float* __restrict__ be2,
               const float* __restrict__ bc1, const float* __restrict__ bc2,
               const float* __restrict__ Wp1, const float* __restrict__ bp1,
               const float* __restrict__ Wp2, const float* __restrict__ bp2,
               const float* __restrict__ Wn1, const float* __restrict__ bn1,
               const float* __restrict__ Wn2, const float* __restrict__ bn2,
               const float* __restrict__ G, const float* __restrict__ Base,
               const unsigned short* __restrict__ w2h, const unsigned short* __restrict__ w2l,
               const unsigned short* __restrict__ w3h, const unsigned short* __restrict__ w3l,
               const unsigned short* __restrict__ w4h, const unsigned short* __restrict__ w4l,
               float* __restrict__ out)
{
  __shared__ unsigned short sAct[2 * 8192];  // bufA | bufB, [j 0..127][k 0..63] swizzled
  __shared__ float sMaskL[128];
  __shared__ float sBase[64], sW1n[64], sHi[64];
  __shared__ float sB2[64], sB3[64], sB4[32];
  __shared__ float sHe[64], sCombP[4][48], sCN[32], sTmp[64], sHcomb[64];

  const int tid  = (int)threadIdx.x;
  const int blk  = (int)blockIdx.x;
  const int b    = blk >> 9;
  const int i    = blk & 511;
  const int lane = tid & 63;
  const int wid  = tid >> 6;
  const int l15  = lane & 15;
  const int lg   = lane >> 4;            // 0..3
  const int mb   = wid * 16;             // feat block (L2/C1)
  const int m2   = wid & 1;              // c-block (C2)
  const int jh   = (wid >> 1) * 16;      // C2 j sub-block

  const size_t mrow = ((size_t)(b * NN + i)) * NN;

  if (tid < 64) {
    sBase[tid] = Base[((size_t)(b * NN + i)) * 64 + tid];
    sW1n[tid]  = We1[128 * 64 + tid];
    sHi[tid]   = h[((size_t)(b * NN + i)) * 64 + tid];
    sB2[tid]   = be2[tid];
    sB3[tid]   = bc1[tid];
  }
  if (tid < 32) sB4[tid] = bc2[tid];
  const float xi0 = x[((size_t)(b * NN + i)) * 3 + 0];
  const float xi1 = x[((size_t)(b * NN + i)) * 3 + 1];
  const float xi2 = x[((size_t)(b * NN + i)) * 3 + 2];

  // weight A-frags in registers: w2/w3 full (16 feats per wave), w4 one c-block
  short8v w2hF[2], w2lF[2], w3hF[2], w3lF[2], w4hF[2], w4lF[2];
  #pragma unroll
  for (int ks = 0; ks < 2; ++ks) {
    const int ko = ks * 32 + lg * 8;
    w2hF[ks] = *(const short8v*)&w2h[(mb + l15) * 64 + ko];
    w2lF[ks] = *(const short8v*)&w2l[(mb + l15) * 64 + ko];
    w3hF[ks] = *(const short8v*)&w3h[(mb + l15) * 64 + ko];
    w3lF[ks] = *(const short8v*)&w3l[(mb + l15) * 64 + ko];
    w4hF[ks] = *(const short8v*)&w4h[(m2 * 16 + l15) * 64 + ko];
    w4lF[ks] = *(const short8v*)&w4l[(m2 * 16 + l15) * 64 + ko];
  }

  float heAcc[4] = {0.f, 0.f, 0.f, 0.f};
  float cAcc[4][3] = {};

  __syncthreads();   // prologue staging complete

  for (int jt = 0; jt < 4; ++jt) {
    const int jb = jt * 128;

    // ---- L1: act1 = silu(G + Base + n2*We1n) -> bufA ; stash mask ----
    #pragma unroll
    for (int jj = 0; jj < 2; ++jj) {
      const int jloc = jj * 64 + wid * 16 + l15;
      const int j = jb + jloc;
      const size_t xo = ((size_t)(b * NN + j)) * 3;
      const float dx = x[xo + 0] - xi0;
      const float dy = x[xo + 1] - xi1;
      const float dz = x[xo + 2] - xi2;
      const float n2 = dx * dx + dy * dy + dz * dz;
      if (lg == 0) sMaskL[jloc] = mask[mrow + j];
      #pragma unroll
      for (int kk = 0; kk < 4; ++kk) {
        const int kb = lg * 16 + kk * 4;
        const float4 g4 = *(const float4*)&G[((size_t)(b * NN + j)) * 64 + kb];
        const float4 bs = *(const float4*)&sBase[kb];
        const float4 wn = *(const float4*)&sW1n[kb];
        const float v0 = silu_f(g4.x + bs.x + n2 * wn.x);
        const float v1 = silu_f(g4.y + bs.y + n2 * wn.y);
        const float v2 = silu_f(g4.z + bs.z + n2 * wn.z);
        const float v3 = silu_f(g4.w + bs.w + n2 * wn.w);
        pack_store4(sAct, AIDX(jloc, kb), v0, v1, v2, v3);
      }
    }
    __syncthreads();   // B: bufA + sMaskL ready

    // ---- L2: bufA -> bufB ; h_e accum ----
    {
      const f32x4 bias = *(const f32x4*)&sB2[mb + lg * 4];
      #pragma unroll
      for (int nf = 0; nf < 8; ++nf) {
        const int jn = nf * 16 + l15;
        f32x4 acc = bias;
        #pragma unroll
        for (int ks = 0; ks < 2; ++ks) {
          const short8v bh = *(const short8v*)&sAct[AIDX(jn, ks * 32 + lg * 8)];
          acc = __builtin_amdgcn_mfma_f32_16x16x32_bf16(w2hF[ks], bh, acc, 0, 0, 0);
          acc = __builtin_amdgcn_mfma_f32_16x16x32_bf16(w2lF[ks], bh, acc, 0, 0, 0);
        }
        const float m = sMaskL[jn];
        float v[4];
        #pragma unroll
        for (int r = 0; r < 4; ++r) { v[r] = silu_f(acc[r]); heAcc[r] = fmaf(v[r], m, heAcc[r]); }
        pack_store4(sAct, 8192 + AIDX(jn, mb + lg * 4), v[0], v[1], v[2], v[3]);
      }
    }
    __syncthreads();   // C: bufB ready (all bufA reads done)

    // ---- C1: bufB -> bufA ----
    {
      const f32x4 bias = *(const f32x4*)&sB3[mb + lg * 4];
      #pragma unroll
      for (int nf = 0; nf < 8; ++nf) {
        const int jn = nf * 16 + l15;
        f32x4 acc = bias;
        #pragma unroll
        for (int ks = 0; ks < 2; ++ks) {
          const short8v bh = *(const short8v*)&sAct[8192 + AIDX(jn, ks * 32 + lg * 8)];
          acc = __builtin_amdgcn_mfma_f32_16x16x32_bf16(w3hF[ks], bh, acc, 0, 0, 0);
          acc = __builtin_amdgcn_mfma_f32_16x16x32_bf16(w3lF[ks], bh, acc, 0, 0, 0);
        }
        float v[4];
        #pragma unroll
        for (int r = 0; r < 4; ++r) v[r] = silu_f(acc[r]);
        pack_store4(sAct, AIDX(jn, mb + lg * 4), v[0], v[1], v[2], v[3]);
      }
    }
    __syncthreads();   // D: bufA(act3) ready

    // ---- C2: bufA ; vec*mask recomputed IN-PHASE (no cross-barrier regs) ----
    {
      const f32x4 bias = *(const f32x4*)&sB4[m2 * 16 + lg * 4];
      #pragma unroll
      for (int jj = 0; jj < 4; ++jj) {
        const int jloc = jj * 32 + jh + l15;   // 0..127, all 8 j-blocks over 4 waves
        const int j = jb + jloc;
        const size_t xo = ((size_t)(b * NN + j)) * 3;
        const float dx = x[xo + 0] - xi0;
        const float dy = x[xo + 1] - xi1;
        const float dz = x[xo + 2] - xi2;
        const float n2 = dx * dx + dy * dy + dz * dz;
        const float inv = __builtin_amdgcn_rcpf(n2 * n2 + 1e-10f);
        const float m = mask[mrow + j];
        const float vm0 = dx * inv * m, vm1 = dy * inv * m, vm2 = dz * inv * m;
        const short8v bh0 = *(const short8v*)&sAct[AIDX(jloc, lg * 8)];
        const short8v bh1 = *(const short8v*)&sAct[AIDX(jloc, 32 + lg * 8)];
        f32x4 acc = bias;
        acc = __builtin_amdgcn_mfma_f32_16x16x32_bf16(w4hF[0], bh0, acc, 0, 0, 0);
        acc = __builtin_amdgcn_mfma_f32_16x16x32_bf16(w4lF[0], bh0, acc, 0, 0, 0);
        acc = __builtin_amdgcn_mfma_f32_16x16x32_bf16(w4hF[1], bh1, acc, 0, 0, 0);
        acc = __builtin_amdgcn_mfma_f32_16x16x32_bf16(w4lF[1], bh1, acc, 0, 0, 0);
        #pragma unroll
        for (int r = 0; r < 4; ++r) {
          cAcc[r][0] = fmaf(acc[r], vm0, cAcc[r][0]);
          cAcc[r][1] = fmaf(acc[r], vm1, cAcc[r][1]);
          cAcc[r][2] = fmaf(acc[r], vm2, cAcc[r][2]);
        }
      }
    }
    __syncthreads();   // E: C2 reads of bufA done (next L1 overwrites bufA)
  }

  // -------- reductions --------
  #pragma unroll
  for (int r = 0; r < 4; ++r) {
    float s = heAcc[r];
    s += __shfl_xor(s, 1); s += __shfl_xor(s, 2); s += __shfl_xor(s, 4); s += __shfl_xor(s, 8);
    if (l15 == 0) sHe[mb + lg * 4 + r] = s;
  }
  #pragma unroll
  for (int r = 0; r < 4; ++r)
    #pragma unroll
    for (int d = 0; d < 3; ++d) {
      float s = cAcc[r][d];
      s += __shfl_xor(s, 1); s += __shfl_xor(s, 2); s += __shfl_xor(s, 4); s += __shfl_xor(s, 8);
      if (l15 == 0) sCombP[wid][(lg * 4 + r) * 3 + d] = s;
    }
  __syncthreads();
  if (tid < 32) {
    const int c = tid, cm2 = c >> 4, cl = c & 15;
    const float s0 = sCombP[cm2][cl * 3 + 0] + sCombP[cm2 + 2][cl * 3 + 0];
    const float s1 = sCombP[cm2][cl * 3 + 1] + sCombP[cm2 + 2][cl * 3 + 1];
    const float s2 = sCombP[cm2][cl * 3 + 2] + sCombP[cm2 + 2][cl * 3 + 2];
    sCN[c] = s0 * s0 + s1 * s1 + s2 * s2;
  }
  __syncthreads();

  // -------- epilogue MLPs (fp32, tiny) --------
  if (tid < 64) {
    float s = bp1[tid];
    #pragma unroll 8
    for (int c = 0; c < 32; ++c) s = fmaf(sCN[c], Wp1[c * 64 + tid], s);
    sTmp[tid] = silu_f(s);
  }
  __syncthreads();
  if (tid < 64) {
    float s = bp2[tid];
    #pragma unroll 16
    for (int k = 0; k < 64; ++k) s = fmaf(sTmp[k], Wp2[k * 64 + tid], s);
    sHcomb[tid] = s;
  }
  __syncthreads();
  if (tid < 64) {
    float s = bn1[tid];
    #pragma unroll 16
    for (int m = 0; m < 64; ++m) s = fmaf(sHi[m],    Wn1[m * 64 + tid],         s);
    #pragma unroll 16
    for (int m = 0; m < 64; ++m) s = fmaf(sHe[m],    Wn1[(64 + m) * 64 + tid],  s);
    #pragma unroll 16
    for (int m = 0; m < 64; ++m) s = fmaf(sHcomb[m], Wn1[(128 + m) * 64 + tid], s);
    sTmp[tid] = silu_f(s);
  }
  __syncthreads();
  if (tid < 64) {
    float s = bn2[tid];
    #pragma unroll 16
    for (int k = 0; k < 64; ++k) s = fmaf(sTmp[k], Wn2[k * 64 + tid], s);
    out[((size_t)(b * NN + i)) * 64 + tid] = sHi[tid] + s;
  } else if (tid < 67) {
    const int d = tid - 64;
    out[(size_t)BB * NN * FF + ((size_t)(b * NN + i)) * 3 + d] = x[((size_t)(b * NN + i)) * 3 + d];
  }
}

extern "C" void kernel_launch(void* const* d_in, const int* in_sizes, int n_in,
                              void* d_out, int out_size, void* d_ws, size_t ws_size,
                              hipStream_t stream) {
  const float* h    = (const float*)d_in[0];
  const float* x    = (const float*)d_in[1];
  const float* mask = (const float*)d_in[2];
  const float* We1  = (const float*)d_in[3];
  const float* be1  = (const float*)d_in[4];
  const float* We2  = (const float*)d_in[5];
  const float* be2  = (const float*)d_in[6];
  const float* Wc1  = (const float*)d_in[7];
  const float* bc1  = (const float*)d_in[8];
  const float* Wc2  = (const float*)d_in[9];
  const float* bc2  = (const float*)d_in[10];
  const float* Wp1  = (const float*)d_in[11];
  const float* bp1  = (const float*)d_in[12];
  const float* Wp2  = (const float*)d_in[13];
  const float* bp2  = (const float*)d_in[14];
  const float* Wn1  = (const float*)d_in[15];
  const float* bn1  = (const float*)d_in[16];
  const float* Wn2  = (const float*)d_in[17];
  const float* bn2  = (const float*)d_in[18];
  float* out = (float*)d_out;

  float* G    = (float*)d_ws;                       // 2048*64 f32
  float* Base = G + 2048 * 64;                      // 2048*64 f32
  unsigned short* w2h = (unsigned short*)(Base + 2048 * 64);
  unsigned short* w2l = w2h + 4096;
  unsigned short* w3h = w2l + 4096;
  unsigned short* w3l = w3h + 4096;
  unsigned short* w4h = w3l + 4096;
  unsigned short* w4l = w4h + 2048;

  hipLaunchKernelGGL(sake_prep, dim3(65), dim3(256), 0, stream,
                     h, We1, be1, We2, Wc1, Wc2, G, Base,
                     w2h, w2l, w3h, w3l, w4h, w4l);
  hipLaunchKernelGGL(sake_mfma, dim3(BB * NN), dim3(256), 0, stream,
                     h, x, mask, We1, be2, bc1, bc2,
                     Wp1, bp1, Wp2, bp2, Wn1, bn1, Wn2, bn2,
                     G, Base, w2h, w2l, w3h, w3l, w4h, w4l, out);
}

// Round 14
// 107.557 us; speedup vs baseline: 1.5420x; 1.1625x over previous
//
#include <hip/hip_runtime.h>

#define BB 4
#define NN 512
#define FF 64

typedef __attribute__((ext_vector_type(8))) _Float16 half8v;   // 8 f16 = 4 VGPR
typedef __attribute__((ext_vector_type(4))) float f32x4;

__device__ __forceinline__ float silu_f(float v) {
  return v * __builtin_amdgcn_rcpf(1.0f + __expf(-v));
}
// packed f32x2 -> f16x2 (RTZ), low16 = a
__device__ __forceinline__ unsigned cvt_pk_f16(float a, float b) {
  auto r = __builtin_amdgcn_cvt_pkrtz(a, b);   // __fp16 ext_vector(2)
  unsigned u; __builtin_memcpy(&u, &r, 4); return u;
}
__device__ __forceinline__ unsigned short f2h(float w) {
  _Float16 hf = (_Float16)w;          // RNE
  unsigned short us; __builtin_memcpy(&us, &hf, 2); return us;
}

// act LDS addressing: [j][k] f16 rows of 128B, 16B slots XOR-swizzled by j. j in 0..127.
#define AIDX(j, k) ((((j) << 6)) | (((((k) >> 3) ^ ((j) & 7))) << 3) | ((k) & 7))

// ---------------- prep kernel ----------------
// wg 0..63: G[b,j,o] = h_j @ We1[0:64];  Base[b,i,o] = be1 + h_i @ We1[64:128]
// wg 64   : transpose weights -> fp16 [out][in] (NO hi/lo split needed at fp16)
__global__ void sake_prep(const float* __restrict__ h, const float* __restrict__ We1,
                          const float* __restrict__ be1, const float* __restrict__ We2,
                          const float* __restrict__ Wc1, const float* __restrict__ Wc2,
                          float* __restrict__ G, float* __restrict__ Base,
                          unsigned short* __restrict__ w2f,
                          unsigned short* __restrict__ w3f,
                          unsigned short* __restrict__ w4f)
{
  const int wg = (int)blockIdx.x, tid = (int)threadIdx.x;
  if (wg < 64) {
    __shared__ float sH[32][64];
    const int r0 = wg * 32;
    for (int idx = tid; idx < 2048; idx += 256) sH[idx >> 6][idx & 63] = h[r0 * 64 + idx];
    __syncthreads();
    const int rl = tid >> 3;
    const int o0 = (tid & 7) * 8;
    float aG[8], aB[8];
    #pragma unroll
    for (int o = 0; o < 8; ++o) { aG[o] = 0.f; aB[o] = be1[o0 + o]; }
    for (int k = 0; k < 64; ++k) {
      const float hv = sH[rl][k];
      const float4 g0 = *(const float4*)&We1[k * 64 + o0];
      const float4 g1 = *(const float4*)&We1[k * 64 + o0 + 4];
      const float4 b0 = *(const float4*)&We1[(64 + k) * 64 + o0];
      const float4 b1 = *(const float4*)&We1[(64 + k) * 64 + o0 + 4];
      aG[0] = fmaf(hv, g0.x, aG[0]); aG[1] = fmaf(hv, g0.y, aG[1]);
      aG[2] = fmaf(hv, g0.z, aG[2]); aG[3] = fmaf(hv, g0.w, aG[3]);
      aG[4] = fmaf(hv, g1.x, aG[4]); aG[5] = fmaf(hv, g1.y, aG[5]);
      aG[6] = fmaf(hv, g1.z, aG[6]); aG[7] = fmaf(hv, g1.w, aG[7]);
      aB[0] = fmaf(hv, b0.x, aB[0]); aB[1] = fmaf(hv, b0.y, aB[1]);
      aB[2] = fmaf(hv, b0.z, aB[2]); aB[3] = fmaf(hv, b0.w, aB[3]);
      aB[4] = fmaf(hv, b1.x, aB[4]); aB[5] = fmaf(hv, b1.y, aB[5]);
      aB[6] = fmaf(hv, b1.z, aB[6]); aB[7] = fmaf(hv, b1.w, aB[7]);
    }
    const size_t base = (size_t)(r0 + rl) * 64 + o0;
    *(float4*)&G[base]        = make_float4(aG[0], aG[1], aG[2], aG[3]);
    *(float4*)&G[base + 4]    = make_float4(aG[4], aG[5], aG[6], aG[7]);
    *(float4*)&Base[base]     = make_float4(aB[0], aB[1], aB[2], aB[3]);
    *(float4*)&Base[base + 4] = make_float4(aB[4], aB[5], aB[6], aB[7]);
  } else {
    for (int idx = tid; idx < 10240; idx += 256) {
      float w; unsigned short* pf; int pos;
      if (idx < 4096)      { const int o = idx >> 6,          k = idx & 63;
                             w = We2[k * 64 + o]; pf = w2f; pos = o * 64 + k; }
      else if (idx < 8192) { const int t = idx - 4096, o = t >> 6, k = t & 63;
                             w = Wc1[k * 64 + o]; pf = w3f; pos = o * 64 + k; }
      else                 { const int t = idx - 8192, c = t >> 6, k = t & 63;
                             w = Wc2[k * 32 + c]; pf = w4f; pos = c * 64 + k; }
      pf[pos] = f2h(w);
    }
  }
}

__device__ __forceinline__ void pack_store4(unsigned short* sA, int a,
                                            float v0, float v1, float v2, float v3) {
  *(uint2*)&sA[a] = make_uint2(cvt_pk_f16(v0, v1), cvt_pk_f16(v2, v3));
}

// ---------------- main kernel ----------------
// R8 base (best measured: 124.5us): TILE=128 (4 tiles), 2-buffer ping-pong,
// 4 barriers/tile, LDS 36.4KB, (256,3) -> 84 VGPR / 3 blocks/CU (stable point;
// any >=4 blocks/CU request triggers allocator over-shrink + spills R4/R6/R10;
// amdgpu_num_vgpr ignored R12).
// CHANGE: split-bf16 -> plain fp16 MFMA (mfma_f32_16x16x32_f16). fp16's 10-bit
// mantissa makes the hi/lo weight split unnecessary: MFMA count HALVES
// (shorter dep chains), weight A-frags 48->24 VGPR (ILP headroom at fixed 84).
// Accuracy: act RTZ 2^-10 (better than bf16 RNE 2^-9) + weight RNE 2^-12.
__global__ __launch_bounds__(256, 3)
void sake_mfma(const float* __restrict__ h, const float* __restrict__ x,
               const float* __restrict__ mask,
               const float* __restrict__ We1, const float* __restrict__ be2,
               const float* __restrict__ bc1, const float* __restrict__ bc2,
               const float* __restrict__ Wp1, const float* __restrict__ bp1,
               const float* __restrict__ Wp2, const float* __restrict__ bp2,
               const float* __restrict__ Wn1, const float* __restrict__ bn1,
               const float* __restrict__ Wn2, const float* __restrict__ bn2,
               const float* __restrict__ G, const float* __restrict__ Base,
               const unsigned short* __restrict__ w2f,
               const unsigned short* __restrict__ w3f,
               const unsigned short* __restrict__ w4f,
               float* __restrict__ out)
{
  __shared__ unsigned short sAct[2 * 8192];  // bufA | bufB, [j 0..127][k 0..63] swizzled, f16
  __shared__ float sMaskL[128];
  __shared__ float sBase[64], sW1n[64], sHi[64];
  __shared__ float sB2[64], sB3[64], sB4[32];
  __shared__ float sHe[64], sCombP[4][48], sCN[32], sTmp[64], sHcomb[64];

  const int tid  = (int)threadIdx.x;
  const int blk  = (int)blockIdx.x;
  const int b    = blk >> 9;
  const int i    = blk & 511;
  const int lane = tid & 63;
  const int wid  = tid >> 6;
  const int l15  = lane & 15;
  const int lg   = lane >> 4;            // 0..3
  const int mb   = wid * 16;             // feat block (L2/C1)
  const int m2   = wid & 1;              // c-block (C2)
  const int jh   = (wid >> 1) * 16;      // C2 j sub-block

  const size_t mrow = ((size_t)(b * NN + i)) * NN;

  if (tid < 64) {
    sBase[tid] = Base[((size_t)(b * NN + i)) * 64 + tid];
    sW1n[tid]  = We1[128 * 64 + tid];
    sHi[tid]   = h[((size_t)(b * NN + i)) * 64 + tid];
    sB2[tid]   = be2[tid];
    sB3[tid]   = bc1[tid];
  }
  if (tid < 32) sB4[tid] = bc2[tid];
  const float xi0 = x[((size_t)(b * NN + i)) * 3 + 0];
  const float xi1 = x[((size_t)(b * NN + i)) * 3 + 1];
  const float xi2 = x[((size_t)(b * NN + i)) * 3 + 2];

  // weight A-frags in registers (fp16, single term): 24 VGPR total
  half8v w2F[2], w3F[2], w4F[2];
  #pragma unroll
  for (int ks = 0; ks < 2; ++ks) {
    const int ko = ks * 32 + lg * 8;
    w2F[ks] = *(const half8v*)&w2f[(mb + l15) * 64 + ko];
    w3F[ks] = *(const half8v*)&w3f[(mb + l15) * 64 + ko];
    w4F[ks] = *(const half8v*)&w4f[(m2 * 16 + l15) * 64 + ko];
  }

  float heAcc[4] = {0.f, 0.f, 0.f, 0.f};
  float cAcc[4][3] = {};

  __syncthreads();   // prologue staging complete

  for (int jt = 0; jt < 4; ++jt) {
    const int jb = jt * 128;

    // ---- L1: act1 = silu(G + Base + n2*We1n) -> bufA ; stash mask ----
    #pragma unroll
    for (int jj = 0; jj < 2; ++jj) {
      const int jloc = jj * 64 + wid * 16 + l15;
      const int j = jb + jloc;
      const size_t xo = ((size_t)(b * NN + j)) * 3;
      const float dx = x[xo + 0] - xi0;
      const float dy = x[xo + 1] - xi1;
      const float dz = x[xo + 2] - xi2;
      const float n2 = dx * dx + dy * dy + dz * dz;
      if (lg == 0) sMaskL[jloc] = mask[mrow + j];
      #pragma unroll
      for (int kk = 0; kk < 4; ++kk) {
        const int kb = lg * 16 + kk * 4;
        const float4 g4 = *(const float4*)&G[((size_t)(b * NN + j)) * 64 + kb];
        const float4 bs = *(const float4*)&sBase[kb];
        const float4 wn = *(const float4*)&sW1n[kb];
        const float v0 = silu_f(g4.x + bs.x + n2 * wn.x);
        const float v1 = silu_f(g4.y + bs.y + n2 * wn.y);
        const float v2 = silu_f(g4.z + bs.z + n2 * wn.z);
        const float v3 = silu_f(g4.w + bs.w + n2 * wn.w);
        pack_store4(sAct, AIDX(jloc, kb), v0, v1, v2, v3);
      }
    }
    __syncthreads();   // B: bufA + sMaskL ready

    // ---- L2: bufA -> bufB ; h_e accum ----
    {
      const f32x4 bias = *(const f32x4*)&sB2[mb + lg * 4];
      #pragma unroll
      for (int nf = 0; nf < 8; ++nf) {
        const int jn = nf * 16 + l15;
        f32x4 acc = bias;
        #pragma unroll
        for (int ks = 0; ks < 2; ++ks) {
          const half8v bh = *(const half8v*)&sAct[AIDX(jn, ks * 32 + lg * 8)];
          acc = __builtin_amdgcn_mfma_f32_16x16x32_f16(w2F[ks], bh, acc, 0, 0, 0);
        }
        const float m = sMaskL[jn];
        float v[4];
        #pragma unroll
        for (int r = 0; r < 4; ++r) { v[r] = silu_f(acc[r]); heAcc[r] = fmaf(v[r], m, heAcc[r]); }
        pack_store4(sAct, 8192 + AIDX(jn, mb + lg * 4), v[0], v[1], v[2], v[3]);
      }
    }
    __syncthreads();   // C: bufB ready (all bufA reads done)

    // ---- C1: bufB -> bufA ----
    {
      const f32x4 bias = *(const f32x4*)&sB3[mb + lg * 4];
      #pragma unroll
      for (int nf = 0; nf < 8; ++nf) {
        const int jn = nf * 16 + l15;
        f32x4 acc = bias;
        #pragma unroll
        for (int ks = 0; ks < 2; ++ks) {
          const half8v bh = *(const half8v*)&sAct[8192 + AIDX(jn, ks * 32 + lg * 8)];
          acc = __builtin_amdgcn_mfma_f32_16x16x32_f16(w3F[ks], bh, acc, 0, 0, 0);
        }
        float v[4];
        #pragma unroll
        for (int r = 0; r < 4; ++r) v[r] = silu_f(acc[r]);
        pack_store4(sAct, AIDX(jn, mb + lg * 4), v[0], v[1], v[2], v[3]);
      }
    }
    __syncthreads();   // D: bufA(act3) ready

    // ---- C2: bufA ; vec*mask recomputed IN-PHASE (no cross-barrier regs) ----
    {
      const f32x4 bias = *(const f32x4*)&sB4[m2 * 16 + lg * 4];
      #pragma unroll
      for (int jj = 0; jj < 4; ++jj) {
        const int jloc = jj * 32 + jh + l15;   // 0..127, all 8 j-blocks over 4 waves
        const int j = jb + jloc;
        const size_t xo = ((size_t)(b * NN + j)) * 3;
        const float dx = x[xo + 0] - xi0;
        const float dy = x[xo + 1] - xi1;
        const float dz = x[xo + 2] - xi2;
        const float n2 = dx * dx + dy * dy + dz * dz;
        const float inv = __builtin_amdgcn_rcpf(n2 * n2 + 1e-10f);
        const float m = mask[mrow + j];
        const float vm0 = dx * inv * m, vm1 = dy * inv * m, vm2 = dz * inv * m;
        const half8v bh0 = *(const half8v*)&sAct[AIDX(jloc, lg * 8)];
        const half8v bh1 = *(const half8v*)&sAct[AIDX(jloc, 32 + lg * 8)];
        f32x4 acc = bias;
        acc = __builtin_amdgcn_mfma_f32_16x16x32_f16(w4F[0], bh0, acc, 0, 0, 0);
        acc = __builtin_amdgcn_mfma_f32_16x16x32_f16(w4F[1], bh1, acc, 0, 0, 0);
        #pragma unroll
        for (int r = 0; r < 4; ++r) {
          cAcc[r][0] = fmaf(acc[r], vm0, cAcc[r][0]);
          cAcc[r][1] = fmaf(acc[r], vm1, cAcc[r][1]);
          cAcc[r][2] = fmaf(acc[r], vm2, cAcc[r][2]);
        }
      }
    }
    __syncthreads();   // E: C2 reads of bufA done (next L1 overwrites bufA)
  }

  // -------- reductions --------
  #pragma unroll
  for (int r = 0; r < 4; ++r) {
    float s = heAcc[r];
    s += __shfl_xor(s, 1); s += __shfl_xor(s, 2); s += __shfl_xor(s, 4); s += __shfl_xor(s, 8);
    if (l15 == 0) sHe[mb + lg * 4 + r] = s;
  }
  #pragma unroll
  for (int r = 0; r < 4; ++r)
    #pragma unroll
    for (int d = 0; d < 3; ++d) {
      float s = cAcc[r][d];
      s += __shfl_xor(s, 1); s += __shfl_xor(s, 2); s += __shfl_xor(s, 4); s += __shfl_xor(s, 8);
      if (l15 == 0) sCombP[wid][(lg * 4 + r) * 3 + d] = s;
    }
  __syncthreads();
  if (tid < 32) {
    const int c = tid, cm2 = c >> 4, cl = c & 15;
    const float s0 = sCombP[cm2][cl * 3 + 0] + sCombP[cm2 + 2][cl * 3 + 0];
    const float s1 = sCombP[cm2][cl * 3 + 1] + sCombP[cm2 + 2][cl * 3 + 1];
    const float s2 = sCombP[cm2][cl * 3 + 2] + sCombP[cm2 + 2][cl * 3 + 2];
    sCN[c] = s0 * s0 + s1 * s1 + s2 * s2;
  }
  __syncthreads();

  // -------- epilogue MLPs (fp32, tiny) --------
  if (tid < 64) {
    float s = bp1[tid];
    #pragma unroll 8
    for (int c = 0; c < 32; ++c) s = fmaf(sCN[c], Wp1[c * 64 + tid], s);
    sTmp[tid] = silu_f(s);
  }
  __syncthreads();
  if (tid < 64) {
    float s = bp2[tid];
    #pragma unroll 16
    for (int k = 0; k < 64; ++k) s = fmaf(sTmp[k], Wp2[k * 64 + tid], s);
    sHcomb[tid] = s;
  }
  __syncthreads();
  if (tid < 64) {
    float s = bn1[tid];
    #pragma unroll 16
    for (int m = 0; m < 64; ++m) s = fmaf(sHi[m],    Wn1[m * 64 + tid],         s);
    #pragma unroll 16
    for (int m = 0; m < 64; ++m) s = fmaf(sHe[m],    Wn1[(64 + m) * 64 + tid],  s);
    #pragma unroll 16
    for (int m = 0; m < 64; ++m) s = fmaf(sHcomb[m], Wn1[(128 + m) * 64 + tid], s);
    sTmp[tid] = silu_f(s);
  }
  __syncthreads();
  if (tid < 64) {
    float s = bn2[tid];
    #pragma unroll 16
    for (int k = 0; k < 64; ++k) s = fmaf(sTmp[k], Wn2[k * 64 + tid], s);
    out[((size_t)(b * NN + i)) * 64 + tid] = sHi[tid] + s;
  } else if (tid < 67) {
    const int d = tid - 64;
    out[(size_t)BB * NN * FF + ((size_t)(b * NN + i)) * 3 + d] = x[((size_t)(b * NN + i)) * 3 + d];
  }
}

extern "C" void kernel_launch(void* const* d_in, const int* in_sizes, int n_in,
                              void* d_out, int out_size, void* d_ws, size_t ws_size,
                              hipStream_t stream) {
  const float* h    = (const float*)d_in[0];
  const float* x    = (const float*)d_in[1];
  const float* mask = (const float*)d_in[2];
  const float* We1  = (const float*)d_in[3];
  const float* be1  = (const float*)d_in[4];
  const float* We2  = (const float*)d_in[5];
  const float* be2  = (const float*)d_in[6];
  const float* Wc1  = (const float*)d_in[7];
  const float* bc1  = (const float*)d_in[8];
  const float* Wc2  = (const float*)d_in[9];
  const float* bc2  = (const float*)d_in[10];
  const float* Wp1  = (const float*)d_in[11];
  const float* bp1  = (const float*)d_in[12];
  const float* Wp2  = (const float*)d_in[13];
  const float* bp2  = (const float*)d_in[14];
  const float* Wn1  = (const float*)d_in[15];
  const float* bn1  = (const float*)d_in[16];
  const float* Wn2  = (const float*)d_in[17];
  const float* bn2  = (const float*)d_in[18];
  float* out = (float*)d_out;

  float* G    = (float*)d_ws;                       // 2048*64 f32
  float* Base = G + 2048 * 64;                      // 2048*64 f32
  unsigned short* w2f = (unsigned short*)(Base + 2048 * 64);
  unsigned short* w3f = w2f + 4096;
  unsigned short* w4f = w3f + 4096;

  hipLaunchKernelGGL(sake_prep, dim3(65), dim3(256), 0, stream,
                     h, We1, be1, We2, Wc1, Wc2, G, Base, w2f, w3f, w4f);
  hipLaunchKernelGGL(sake_mfma, dim3(BB * NN), dim3(256), 0, stream,
                     h, x, mask, We1, be2, bc1, bc2,
                     Wp1, bp1, Wp2, bp2, Wn1, bn1, Wn2, bn2,
                     G, Base, w2f, w3f, w4f, out);
}